// Round 7
// baseline (62.283 us; speedup 1.0000x reference)
//
#include <hip/hip_runtime.h>

// GaussianKernel: out[row, o] = exp(-(||x_row||^2 - 2 x_row.w_o + ||w_o||^2)) + b[o]
// x: 262144 rows x 32 fp32; w: [32,128]; b: [128]; out fp32.
//
// Round-6 post-mortem: "s"-constraint failed because row_base (derived from
// threadIdx) is divergence-tagged -> pointer landed in VGPRs -> s_load rejected.
// Fix: readfirstlane(row_base) to get a provably-uniform value before forming
// the pointer. Rest per round-5 plan: 2-deep ping-pong s_load_dwordx16 pipeline,
// lgkmcnt(0)+sched_barrier(0) after the covering FMAs (rule #18), per-lane xsq
// broadcast via readlane (no LDS).

typedef float vf16 __attribute__((ext_vector_type(16)));

constexpr int C_DIM  = 32;
constexpr int OUT_DIM = 128;
constexpr int ROWS_PER_WAVE = 64;   // == wavefront size: lane l owns xsq of row_base+l
constexpr float LOG2E = 1.4426950408889634f;

// Two 64B scalar loads of one x row (128 B) into 32 SGPRs. Early-clobber so the
// destinations can't alias the address pair (second s_load still reads %2).
#define SLOAD_ROW(dlo, dhi, ptr)                                              \
    asm volatile("s_load_dwordx16 %0, %2, 0x0\n\t"                            \
                 "s_load_dwordx16 %1, %2, 0x40"                               \
                 : "=&s"(dlo), "=&s"(dhi) : "s"(ptr))

__global__ __launch_bounds__(256, 4)
void gaussian_rbf_kernel(const float* __restrict__ x,
                         const float* __restrict__ w,
                         const float* __restrict__ bias,
                         float* __restrict__ out,
                         int total_rows)
{
    const int lane = threadIdx.x & 63;
    const int wid  = threadIdx.x >> 6;
    const int colHalf = wid & 1;   // which 64-column half this wave owns
    const int rowGrp  = wid >> 1;  // which 64-row group this wave owns
    const int o = colHalf * 64 + lane;

    const int row_base = (blockIdx.x * 2 + rowGrp) * ROWS_PER_WAVE;
    if (row_base >= total_rows) return;

    // --- per-lane xsq: lane l computes ||x_{row_base+l}||^2 (vector loads) ---
    float xsq_l = 0.f;
    {
        const float4* xp = reinterpret_cast<const float4*>(
            x + (long)(row_base + lane) * C_DIM);
#pragma unroll
        for (int k = 0; k < 8; ++k) {
            const float4 v = xp[k];
            xsq_l = fmaf(v.x, v.x, xsq_l);
            xsq_l = fmaf(v.y, v.y, xsq_l);
            xsq_l = fmaf(v.z, v.z, xsq_l);
            xsq_l = fmaf(v.w, v.w, xsq_l);
        }
    }

    // --- one w column per lane, pinned in VGPRs ---
    float wc[C_DIM];
    float wsq = 0.f;
#pragma unroll
    for (int c = 0; c < C_DIM; ++c) {
        wc[c] = w[c * OUT_DIM + o];
        wsq = fmaf(wc[c], wc[c], wsq);
    }
#pragma unroll
    for (int c = 0; c < C_DIM; ++c)
        asm volatile("" : "+v"(wc[c]));   // forbid rematerialization into the loop
    const float bo = bias[o];
    const float base = -LOG2E * wsq;      // fold -log2e*||w||^2

    // Wave-uniform row base, laundered so divergence analysis proves it:
    // the s_load address must live in an SGPR pair.
    const int urow_base = __builtin_amdgcn_readfirstlane(row_base);
    const float* xrow = x + (long)urow_base * C_DIM;
    float* orow = out + (long)row_base * OUT_DIM + o;

    // dot(X, wc) with 4 independent chains; X elements are SGPRs (v_fma v,s,v).
    auto compute_row = [&](int r, const vf16& Xlo, const vf16& Xhi) {
        float d0 = 0.f, d1 = 0.f, d2 = 0.f, d3 = 0.f;
#pragma unroll
        for (int c = 0; c < 8; ++c) {
            d0 = fmaf(Xlo[c],     wc[c],      d0);
            d1 = fmaf(Xlo[c + 8], wc[c + 8],  d1);
            d2 = fmaf(Xhi[c],     wc[c + 16], d2);
            d3 = fmaf(Xhi[c + 8], wc[c + 24], d3);
        }
        const float d = (d0 + d1) + (d2 + d3);
        // broadcast this row's xsq from lane r (uniform index -> SGPR result)
        const float sxsq = __int_as_float(
            __builtin_amdgcn_readlane(__float_as_int(xsq_l), r));
        const float a = fmaf(d, 2.f * LOG2E, fmaf(sxsq, -LOG2E, base));
        orow[(long)r * OUT_DIM] = exp2f(a) + bo;
    };

    vf16 xa0, xa1, xb0, xb1;
    // prologue: load row 0 and wait
    SLOAD_ROW(xa0, xa1, xrow);
    asm volatile("s_waitcnt lgkmcnt(0)");
    __builtin_amdgcn_sched_barrier(0);

    for (int r = 0; r < ROWS_PER_WAVE; r += 2) {
        // issue row r+1 loads, then compute row r (covers the latency)
        SLOAD_ROW(xb0, xb1, xrow + (r + 1) * C_DIM);
        compute_row(r, xa0, xa1);
        asm volatile("s_waitcnt lgkmcnt(0)");
        __builtin_amdgcn_sched_barrier(0);   // rule #18: no hoist above the wait

        // issue row r+2 loads (clamped in the last iteration), compute row r+1
        const int rn = (r + 2 < ROWS_PER_WAVE) ? (r + 2) : r;
        SLOAD_ROW(xa0, xa1, xrow + rn * C_DIM);
        compute_row(r + 1, xb0, xb1);
        asm volatile("s_waitcnt lgkmcnt(0)");
        __builtin_amdgcn_sched_barrier(0);
    }
}

extern "C" void kernel_launch(void* const* d_in, const int* in_sizes, int n_in,
                              void* d_out, int out_size, void* d_ws, size_t ws_size,
                              hipStream_t stream) {
    const float* x = (const float*)d_in[0];
    const float* w = (const float*)d_in[1];
    const float* b = (const float*)d_in[2];
    float* out = (float*)d_out;

    const int total_rows = in_sizes[0] / C_DIM;                  // 262144
    const int rows_per_block = 2 * ROWS_PER_WAVE;                // 128
    const int nblocks = (total_rows + rows_per_block - 1) / rows_per_block;  // 2048

    gaussian_rbf_kernel<<<nblocks, 256, 0, stream>>>(x, w, b, out, total_rows);
}